// Round 2
// baseline (3309.724 us; speedup 1.0000x reference)
//
#include <hip/hip_runtime.h>

typedef __attribute__((ext_vector_type(8))) short bf16x8;
typedef __attribute__((ext_vector_type(4))) float f32x4;

#define T_STEPS 96
#define BATCH 64
#define HID 2048
#define NGATE 8192

__device__ inline unsigned short f2bf(float f) {
  union { float f; unsigned u; } x; x.f = f;
  unsigned r = x.u + 0x7fffu + ((x.u >> 16) & 1u);
  return (unsigned short)(r >> 16);
}
__device__ inline float bf2f(unsigned short b) {
  union { unsigned u; float f; } x; x.u = ((unsigned)b) << 16;
  return x.f;
}
__device__ inline float sigm(float x) { return 1.f / (1.f + __expf(-x)); }
__device__ inline float tanh_(float x) { return 1.f - 2.f / (__expf(2.f * x) + 1.f); }

// ---------------------------------------------------------------- cast f32->bf16
__global__ __launch_bounds__(256) void cast_bf16(const float* __restrict__ in,
                                                 unsigned short* __restrict__ out,
                                                 int n4) {
  int i = blockIdx.x * 256 + threadIdx.x;
  if (i >= n4) return;
  float4 v = ((const float4*)in)[i];
  ushort4 o;
  o.x = f2bf(v.x); o.y = f2bf(v.y); o.z = f2bf(v.z); o.w = f2bf(v.w);
  ((ushort4*)out)[i] = o;
}

// ---------------------------------------------------------------- gumbel
// JAX >= 0.5 default: jax_threefry_partitionable=True.
// Per-element flat index i (u64 counter): (x0,x1) = (hi32(i), lo32(i)) = (0, i)
// threefry2x32 with key (0, 42); 32-bit bits = out0 ^ out1.
// uniform = max(tiny, f*(1-tiny)+tiny), f = bitcast((bits>>9)|0x3f800000)-1
// gumbel = -log(-log(uniform))
__global__ void gumbel_k(float* __restrict__ g) {
  int p = blockIdx.x * blockDim.x + threadIdx.x;
  if (p >= 12288) return;
  const unsigned k1 = 0u, k2 = 42u;
  unsigned ks[3] = { k1, k2, 0x1BD11BDAu ^ k1 ^ k2 };
  unsigned x0 = 0u + ks[0];            // hi32 of counter
  unsigned x1 = (unsigned)p + ks[1];   // lo32 of counter
  const int rot[2][4] = { {13, 15, 26, 6}, {17, 29, 16, 24} };
  #pragma unroll
  for (int i = 0; i < 5; ++i) {
    #pragma unroll
    for (int j = 0; j < 4; ++j) {
      int r = rot[i & 1][j];
      x0 += x1;
      x1 = (x1 << r) | (x1 >> (32 - r));
      x1 ^= x0;
    }
    x0 += ks[(i + 1) % 3];
    x1 += ks[(i + 2) % 3] + (unsigned)(i + 1);
  }
  unsigned bits = x0 ^ x1;
  union { unsigned u; float f; } v; v.u = (bits >> 9) | 0x3f800000u;
  float f = v.f - 1.f;
  const float tiny = 1.17549435e-38f;
  float u = fmaxf(tiny, f * (1.f - tiny) + tiny);
  g[p] = -logf(-logf(u));
}

// ---------------------------------------------------------------- phase-1 GEMM
// xg[t*64+b][n] = sum_k feature[b][t][k]*W_ih[n][k] + b_ih[n] + b_hh[n]
// A: (6144,2048) bf16 (feature rows m = b*96+t), W: (8192,2048) bf16
__global__ __launch_bounds__(256) void gemm_xg(
    const unsigned short* __restrict__ A,
    const unsigned short* __restrict__ W,
    const float* __restrict__ b_ih, const float* __restrict__ b_hh,
    unsigned short* __restrict__ xg) {
  __shared__ unsigned short As[128 * 32];
  __shared__ unsigned short Bs[128 * 32];
  int bid = blockIdx.x;
  int nb = bid & 63, mb = bid >> 6;      // 64 n-blocks x 48 m-blocks
  int m0 = mb * 128, n0 = nb * 128;
  int tid = threadIdx.x, w = tid >> 6, l = tid & 63;
  int lr = l & 15, lg = l >> 4;
  int wm = (w & 1) * 64, wn = (w >> 1) * 64;
  f32x4 acc[4][4] = {};
  int e0 = w * 512 + l * 8;
  for (int k0 = 0; k0 < 2048; k0 += 32) {
    __syncthreads();
    #pragma unroll
    for (int j = 0; j < 2; ++j) {
      int e = j * 2048 + e0;
      int r = e >> 5, c = e & 31;
      const unsigned short* ga = A + (long)(m0 + r) * 2048 + k0 + c;
      const unsigned short* gb = W + (long)(n0 + r) * 2048 + k0 + c;
      __builtin_amdgcn_global_load_lds(
          (const __attribute__((address_space(1))) unsigned int*)ga,
          (__attribute__((address_space(3))) unsigned int*)&As[j * 2048 + w * 512],
          16, 0, 0);
      __builtin_amdgcn_global_load_lds(
          (const __attribute__((address_space(1))) unsigned int*)gb,
          (__attribute__((address_space(3))) unsigned int*)&Bs[j * 2048 + w * 512],
          16, 0, 0);
    }
    __syncthreads();
    bf16x8 av[4], bv[4];
    #pragma unroll
    for (int i = 0; i < 4; ++i)
      av[i] = *(const bf16x8*)&As[(wm + i * 16 + lr) * 32 + lg * 8];
    #pragma unroll
    for (int i = 0; i < 4; ++i)
      bv[i] = *(const bf16x8*)&Bs[(wn + i * 16 + lr) * 32 + lg * 8];
    #pragma unroll
    for (int i = 0; i < 4; ++i)
      #pragma unroll
      for (int j = 0; j < 4; ++j)
        acc[i][j] = __builtin_amdgcn_mfma_f32_16x16x32_bf16(av[i], bv[j], acc[i][j], 0, 0, 0);
  }
  #pragma unroll
  for (int j = 0; j < 4; ++j) {
    int n = n0 + wn + j * 16 + lr;
    float bias = b_ih[n] + b_hh[n];
    #pragma unroll
    for (int i = 0; i < 4; ++i) {
      #pragma unroll
      for (int r = 0; r < 4; ++r) {
        int m = m0 + wm + i * 16 + lg * 4 + r;
        int bb = m / 96;            // batch
        int tt = m - bb * 96;       // time
        long row = (long)tt * 64 + bb;  // store t-major
        xg[row * 8192 + n] = f2bf(acc[i][j][r] + bias);
      }
    }
  }
}

// ---------------------------------------------------------------- recurrent step
// grid 256 = [mh:2][cb:128]; block 512 = 8 waves: wave = (mt:2) x (gate:4)
__global__ __launch_bounds__(512) void lstm_step(
    const unsigned short* __restrict__ Whh,   // (8192,2048) bf16
    const unsigned short* __restrict__ xg,    // (96,64,8192) bf16
    const unsigned short* __restrict__ Hprev, // (64,2048) bf16
    unsigned short* __restrict__ Hnext,       // (64,2048) bf16
    unsigned short* __restrict__ Call_t,      // (64,2048) bf16 snapshot
    float* __restrict__ Cstate,               // (64,2048) f32
    int t) {
  __shared__ float gl[4][32][16];
  int bid = blockIdx.x;
  int mh = bid >> 7, cb = bid & 127;
  int tid = threadIdx.x, w = tid >> 6, l = tid & 63;
  int lr = l & 15, lg = l >> 4;
  int mt = w & 1, gate = w >> 1;
  int arow = mh * 32 + mt * 16 + lr;
  int wrow = gate * 2048 + cb * 16 + lr;
  const unsigned short* Aptr = Hprev + (long)arow * 2048 + lg * 8;
  const unsigned short* Wptr = Whh + (long)wrow * 2048 + lg * 8;
  f32x4 acc = {};
  #pragma unroll 4
  for (int k0 = 0; k0 < 2048; k0 += 32) {
    bf16x8 a = *(const bf16x8*)(Aptr + k0);
    bf16x8 b = *(const bf16x8*)(Wptr + k0);
    acc = __builtin_amdgcn_mfma_f32_16x16x32_bf16(a, b, acc, 0, 0, 0);
  }
  #pragma unroll
  for (int r = 0; r < 4; ++r)
    gl[gate][mt * 16 + lg * 4 + r][lr] = acc[r];
  __syncthreads();
  // elementwise: one cell per thread (32 batches x 16 cols)
  int bl = tid >> 4, col = tid & 15;
  int bglob = mh * 32 + bl;
  int nb = cb * 16 + col;
  const unsigned short* xrow = xg + ((long)t * 64 + bglob) * 8192;
  float iv = gl[0][bl][col] + bf2f(xrow[nb]);
  float fv = gl[1][bl][col] + bf2f(xrow[2048 + nb]);
  float gv = gl[2][bl][col] + bf2f(xrow[4096 + nb]);
  float ov = gl[3][bl][col] + bf2f(xrow[6144 + nb]);
  long ci = (long)bglob * 2048 + nb;
  float c = sigm(fv) * Cstate[ci] + sigm(iv) * tanh_(gv);
  float h = sigm(ov) * tanh_(c);
  Cstate[ci] = c;
  Call_t[ci] = f2bf(c);
  Hnext[ci] = f2bf(h);
}

// ---------------------------------------------------------------- heads
// one wave per (t,b): 7 dot products over H=2048 + softmax
__global__ __launch_bounds__(256) void heads(
    const unsigned short* __restrict__ Hall,  // (97,64,2048), h(t) at slot t+1
    const unsigned short* __restrict__ Call,  // (96,64,2048)
    const float* __restrict__ Wp, const float* __restrict__ bp,
    const float* __restrict__ Wpc, const float* __restrict__ bpc,
    const float* __restrict__ Wu, const float* __restrict__ bu,
    const float* __restrict__ Wuse, const float* __restrict__ buse,
    const float* __restrict__ gum,
    float* __restrict__ out) {
  int p = blockIdx.x * 4 + (threadIdx.x >> 6);
  int l = threadIdx.x & 63;
  int t = p >> 6, b = p & 63;
  const unsigned short* h = Hall + ((long)(t + 1) * 64 + b) * 2048;
  const unsigned short* c = Call + ((long)t * 64 + b) * 2048;
  float s0 = 0, s1 = 0, sc0 = 0, sc1 = 0, su = 0, q0 = 0, q1 = 0;
  #pragma unroll
  for (int j = 0; j < 8; ++j) {
    int k = j * 256 + l * 4;
    ushort4 hv = *(const ushort4*)(h + k);
    ushort4 cv = *(const ushort4*)(c + k);
    float hf0 = bf2f(hv.x), hf1 = bf2f(hv.y), hf2 = bf2f(hv.z), hf3 = bf2f(hv.w);
    float cf0 = bf2f(cv.x), cf1 = bf2f(cv.y), cf2 = bf2f(cv.z), cf3 = bf2f(cv.w);
    float4 w0 = *(const float4*)(Wp + k);
    float4 w1 = *(const float4*)(Wp + 2048 + k);
    float4 w2 = *(const float4*)(Wpc + k);
    float4 w3 = *(const float4*)(Wpc + 2048 + k);
    float4 w4 = *(const float4*)(Wu + k);
    float4 w5 = *(const float4*)(Wuse + k);
    float4 w6 = *(const float4*)(Wuse + 2048 + k);
    s0 += hf0 * w0.x + hf1 * w0.y + hf2 * w0.z + hf3 * w0.w;
    s1 += hf0 * w1.x + hf1 * w1.y + hf2 * w1.z + hf3 * w1.w;
    sc0 += cf0 * w2.x + cf1 * w2.y + cf2 * w2.z + cf3 * w2.w;
    sc1 += cf0 * w3.x + cf1 * w3.y + cf2 * w3.z + cf3 * w3.w;
    su += hf0 * w4.x + hf1 * w4.y + hf2 * w4.z + hf3 * w4.w;
    q0 += hf0 * w5.x + hf1 * w5.y + hf2 * w5.z + hf3 * w5.w;
    q1 += hf0 * w6.x + hf1 * w6.y + hf2 * w6.z + hf3 * w6.w;
  }
  #pragma unroll
  for (int off = 32; off > 0; off >>= 1) {
    s0 += __shfl_xor(s0, off);
    s1 += __shfl_xor(s1, off);
    sc0 += __shfl_xor(sc0, off);
    sc1 += __shfl_xor(sc1, off);
    su += __shfl_xor(su, off);
    q0 += __shfl_xor(q0, off);
    q1 += __shfl_xor(q1, off);
  }
  if (l == 0) {
    out[(p << 1)] = s0 + bp[0];
    out[(p << 1) + 1] = s1 + bp[1];
    out[12288 + (p << 1)] = sc0 + bpc[0];
    out[12288 + (p << 1) + 1] = sc1 + bpc[1];
    out[24576 + p] = su + bu[0];
    float u0 = q0 + buse[0] + gum[p * 2];
    float u1 = q1 + buse[1] + gum[p * 2 + 1];
    float m = fmaxf(u0, u1);
    float x0 = expf(u0 - m), x1 = expf(u1 - m);
    float inv = 1.f / (x0 + x1);
    if (t >= 1) {
      out[30720 + ((t - 1) * 64 + b) * 2] = x0 * inv;
      out[30720 + ((t - 1) * 64 + b) * 2 + 1] = x1 * inv;
    }
  }
}

// ---------------------------------------------------------------- launch
extern "C" void kernel_launch(void* const* d_in, const int* in_sizes, int n_in,
                              void* d_out, int out_size, void* d_ws, size_t ws_size,
                              hipStream_t stream) {
  const float* feature  = (const float*)d_in[0];
  const float* W_ih     = (const float*)d_in[1];
  const float* W_hh     = (const float*)d_in[2];
  const float* b_ih     = (const float*)d_in[3];
  const float* b_hh     = (const float*)d_in[4];
  const float* W_pred   = (const float*)d_in[5];
  const float* b_pred   = (const float*)d_in[6];
  const float* W_pred_c = (const float*)d_in[7];
  const float* b_pred_c = (const float*)d_in[8];
  const float* W_util   = (const float*)d_in[9];
  const float* b_util   = (const float*)d_in[10];
  const float* W_use    = (const float*)d_in[11];
  const float* b_use    = (const float*)d_in[12];

  char* ws = (char*)d_ws;
  // layout (bytes):
  //   [0, 25165824)            A_bf16 (phase1) / Call snapshots (phase2) -- aliased
  //   [25165824, 58720256)     W bf16 (W_ih for phase1, then W_hh)
  //   [58720256, 159383552)    xg bf16 (96,64,8192)
  //   [159383552, 184811520)   H_all bf16 (97,64,2048)
  //   [184811520, 185335808)   C_state f32 (64,2048)
  //   [185335808, 185384960)   gumbel f32 (96,64,2)
  unsigned short* Abf  = (unsigned short*)(ws + 0);
  unsigned short* Call = (unsigned short*)(ws + 0);
  unsigned short* Wbf  = (unsigned short*)(ws + 25165824L);
  unsigned short* xg   = (unsigned short*)(ws + 58720256L);
  unsigned short* Hall = (unsigned short*)(ws + 159383552L);
  float* Cstate        = (float*)(ws + 184811520L);
  float* gum           = (float*)(ws + 185335808L);
  float* out = (float*)d_out;

  // zero h(-1) and c(-1)
  hipMemsetAsync(Hall, 0, (size_t)BATCH * HID * 2, stream);
  hipMemsetAsync(Cstate, 0, (size_t)BATCH * HID * 4, stream);

  gumbel_k<<<48, 256, 0, stream>>>(gum);

  // casts
  cast_bf16<<<(12582912 / 4) / 256, 256, 0, stream>>>(feature, Abf, 12582912 / 4);
  cast_bf16<<<(16777216 / 4) / 256, 256, 0, stream>>>(W_ih, Wbf, 16777216 / 4);

  // phase 1: x_gates
  gemm_xg<<<3072, 256, 0, stream>>>(Abf, Wbf, b_ih, b_hh, xg);

  // W_hh cast (overwrites W_ih copy)
  cast_bf16<<<(16777216 / 4) / 256, 256, 0, stream>>>(W_hh, Wbf, 16777216 / 4);

  // phase 2: 96 recurrent steps
  for (int t = 0; t < T_STEPS; ++t) {
    lstm_step<<<256, 512, 0, stream>>>(
        Wbf, xg,
        Hall + (long)t * BATCH * HID,
        Hall + (long)(t + 1) * BATCH * HID,
        Call + (long)t * BATCH * HID,
        Cstate, t);
  }

  // heads
  heads<<<1536, 256, 0, stream>>>(Hall, Call,
                                  W_pred, b_pred, W_pred_c, b_pred_c,
                                  W_util, b_util, W_use, b_use,
                                  gum, out);
}

// Round 3
// 1631.339 us; speedup vs baseline: 2.0288x; 2.0288x over previous
//
#include <hip/hip_runtime.h>

typedef __attribute__((ext_vector_type(8))) short bf16x8;
typedef __attribute__((ext_vector_type(4))) float f32x4;

#define T_STEPS 96
#define BATCH 64
#define HID 2048
#define NGATE 8192

#define AS1 __attribute__((address_space(1)))
#define AS3 __attribute__((address_space(3)))

__device__ inline unsigned short f2bf(float f) {
  union { float f; unsigned u; } x; x.f = f;
  unsigned r = x.u + 0x7fffu + ((x.u >> 16) & 1u);
  return (unsigned short)(r >> 16);
}
__device__ inline float bf2f(unsigned short b) {
  union { unsigned u; float f; } x; x.u = ((unsigned)b) << 16;
  return x.f;
}
__device__ inline float sigm(float x) { return 1.f / (1.f + __expf(-x)); }
__device__ inline float tanh_(float x) { return 1.f - 2.f / (__expf(2.f * x) + 1.f); }

// ---------------------------------------------------------------- cast f32->bf16
__global__ __launch_bounds__(256) void cast_bf16(const float* __restrict__ in,
                                                 unsigned short* __restrict__ out,
                                                 int n4) {
  int i = blockIdx.x * 256 + threadIdx.x;
  if (i >= n4) return;
  float4 v = ((const float4*)in)[i];
  ushort4 o;
  o.x = f2bf(v.x); o.y = f2bf(v.y); o.z = f2bf(v.z); o.w = f2bf(v.w);
  ((ushort4*)out)[i] = o;
}

// ---------------------------------------------------------------- gumbel (threefry, partitionable)
__global__ void gumbel_k(float* __restrict__ g) {
  int p = blockIdx.x * blockDim.x + threadIdx.x;
  if (p >= 12288) return;
  const unsigned k1 = 0u, k2 = 42u;
  unsigned ks[3] = { k1, k2, 0x1BD11BDAu ^ k1 ^ k2 };
  unsigned x0 = 0u + ks[0];
  unsigned x1 = (unsigned)p + ks[1];
  const int rot[2][4] = { {13, 15, 26, 6}, {17, 29, 16, 24} };
  #pragma unroll
  for (int i = 0; i < 5; ++i) {
    #pragma unroll
    for (int j = 0; j < 4; ++j) {
      int r = rot[i & 1][j];
      x0 += x1;
      x1 = (x1 << r) | (x1 >> (32 - r));
      x1 ^= x0;
    }
    x0 += ks[(i + 1) % 3];
    x1 += ks[(i + 2) % 3] + (unsigned)(i + 1);
  }
  unsigned bits = x0 ^ x1;
  union { unsigned u; float f; } v; v.u = (bits >> 9) | 0x3f800000u;
  float f = v.f - 1.f;
  const float tiny = 1.17549435e-38f;
  float u = fmaxf(tiny, f * (1.f - tiny) + tiny);
  g[p] = -logf(-logf(u));
}

// ---------------------------------------------------------------- phase-1 GEMM (unchanged, 781 TF)
__global__ __launch_bounds__(256) void gemm_xg(
    const unsigned short* __restrict__ A,
    const unsigned short* __restrict__ W,
    const float* __restrict__ b_ih, const float* __restrict__ b_hh,
    unsigned short* __restrict__ xg) {
  __shared__ unsigned short As[128 * 32];
  __shared__ unsigned short Bs[128 * 32];
  int bid = blockIdx.x;
  int nb = bid & 63, mb = bid >> 6;
  int m0 = mb * 128, n0 = nb * 128;
  int tid = threadIdx.x, w = tid >> 6, l = tid & 63;
  int lr = l & 15, lg = l >> 4;
  int wm = (w & 1) * 64, wn = (w >> 1) * 64;
  f32x4 acc[4][4] = {};
  int e0 = w * 512 + l * 8;
  for (int k0 = 0; k0 < 2048; k0 += 32) {
    __syncthreads();
    #pragma unroll
    for (int j = 0; j < 2; ++j) {
      int e = j * 2048 + e0;
      int r = e >> 5, c = e & 31;
      const unsigned short* ga = A + (long)(m0 + r) * 2048 + k0 + c;
      const unsigned short* gb = W + (long)(n0 + r) * 2048 + k0 + c;
      __builtin_amdgcn_global_load_lds(
          (const AS1 unsigned int*)ga,
          (AS3 unsigned int*)&As[j * 2048 + w * 512], 16, 0, 0);
      __builtin_amdgcn_global_load_lds(
          (const AS1 unsigned int*)gb,
          (AS3 unsigned int*)&Bs[j * 2048 + w * 512], 16, 0, 0);
    }
    __syncthreads();
    bf16x8 av[4], bv[4];
    #pragma unroll
    for (int i = 0; i < 4; ++i)
      av[i] = *(const bf16x8*)&As[(wm + i * 16 + lr) * 32 + lg * 8];
    #pragma unroll
    for (int i = 0; i < 4; ++i)
      bv[i] = *(const bf16x8*)&Bs[(wn + i * 16 + lr) * 32 + lg * 8];
    #pragma unroll
    for (int i = 0; i < 4; ++i)
      #pragma unroll
      for (int j = 0; j < 4; ++j)
        acc[i][j] = __builtin_amdgcn_mfma_f32_16x16x32_bf16(av[i], bv[j], acc[i][j], 0, 0, 0);
  }
  #pragma unroll
  for (int j = 0; j < 4; ++j) {
    int n = n0 + wn + j * 16 + lr;
    float bias = b_ih[n] + b_hh[n];
    #pragma unroll
    for (int i = 0; i < 4; ++i) {
      #pragma unroll
      for (int r = 0; r < 4; ++r) {
        int m = m0 + wm + i * 16 + lg * 4 + r;
        int bb = m / 96;
        int tt = m - bb * 96;
        long row = (long)tt * 64 + bb;
        xg[row * 8192 + n] = f2bf(acc[i][j][r] + bias);
      }
    }
  }
}

// ---------------------------------------------------------------- recurrent step (rewritten)
// grid 128 (col-blocks of 16 cols x 4 gates), block 512 = 8 waves (gate:4 x mtile:2)
// K-step 128, double-buffered LDS staging of A (Hprev 64x128) and B (W 64x128),
// XOR-swizzled (kbyte ^ (row&7)<<4) via pre-swizzled global source + swizzled ds_read.
// W_hh read exactly ONCE per step (32 MB); fused gate-combine + c/h elementwise.
__global__ __launch_bounds__(512) void lstm_step(
    const unsigned short* __restrict__ Whh,   // (8192,2048) bf16
    const unsigned short* __restrict__ xg,    // (96,64,8192) bf16
    const unsigned short* __restrict__ Hprev, // (64,2048) bf16
    unsigned short* __restrict__ Hnext,       // (64,2048) bf16
    unsigned short* __restrict__ Call_t,      // (64,2048) bf16 snapshot
    float* __restrict__ Cstate,               // (64,2048) f32
    int t) {
  __shared__ unsigned char smem[65536];       // 2 bufs x (A 16K + B 16K); gl aliases buf0.A
  const int cb = blockIdx.x;
  const int tid = threadIdx.x;
  const int w = tid >> 6, l = tid & 63;
  const int lr = l & 15, lg = l >> 4;
  const int g = w >> 1, mt = w & 1;

  // staging source addresses: linear LDS slot (row, colb) holds logical kbyte = colb ^ ((row&7)<<4)
  const int srow = tid >> 4;                       // 0..31 per round
  const int kswz = ((tid & 15) * 16) ^ ((srow & 7) << 4);  // byte offset (row&7 == srow&7 for both rounds)
  const unsigned short* aSrc0 = Hprev + (long)srow * 2048 + (kswz >> 1);
  const unsigned short* aSrc1 = Hprev + (long)(32 + srow) * 2048 + (kswz >> 1);
  const int rb0 = srow, rb1 = 32 + srow;
  const unsigned short* bSrc0 = Whh + ((long)((rb0 >> 4) * 2048 + cb * 16 + (rb0 & 15))) * 2048 + (kswz >> 1);
  const unsigned short* bSrc1 = Whh + ((long)((rb1 >> 4) * 2048 + cb * 16 + (rb1 & 15))) * 2048 + (kswz >> 1);
  unsigned char* const lwave = smem + w * 1024;    // wave-uniform LDS base (64 lanes x 16B)

#define STAGE(bufi, k0) do {                                                   \
    unsigned char* lb = lwave + (bufi) * 32768;                                \
    __builtin_amdgcn_global_load_lds((const AS1 unsigned int*)(aSrc0 + (k0)),  \
        (AS3 unsigned int*)(lb), 16, 0, 0);                                    \
    __builtin_amdgcn_global_load_lds((const AS1 unsigned int*)(aSrc1 + (k0)),  \
        (AS3 unsigned int*)(lb + 8192), 16, 0, 0);                             \
    __builtin_amdgcn_global_load_lds((const AS1 unsigned int*)(bSrc0 + (k0)),  \
        (AS3 unsigned int*)(lb + 16384), 16, 0, 0);                            \
    __builtin_amdgcn_global_load_lds((const AS1 unsigned int*)(bSrc1 + (k0)),  \
        (AS3 unsigned int*)(lb + 24576), 16, 0, 0);                            \
  } while (0)

  STAGE(0, 0);
  asm volatile("s_waitcnt vmcnt(0)" ::: "memory");
  __builtin_amdgcn_s_barrier();
  __builtin_amdgcn_sched_barrier(0);

  f32x4 acc0 = {}, acc1 = {};
  const int kx = (lr & 7) << 4;
  const unsigned char* bBase  = smem + 16384 + (g * 16 + lr) * 256;
  const unsigned char* aBase0 = smem + (mt * 32 + lr) * 256;
  const unsigned char* aBase1 = smem + (mt * 32 + 16 + lr) * 256;

  for (int ks = 0; ks < 16; ++ks) {
    const int buf = (ks & 1) * 32768;
    if (ks < 15) STAGE((ks + 1) & 1, (ks + 1) * 128);
    #pragma unroll
    for (int ksub = 0; ksub < 4; ++ksub) {
      int kb = (ksub * 64 + lg * 16) ^ kx;
      bf16x8 b  = *(const bf16x8*)(bBase  + buf + kb);
      bf16x8 a0 = *(const bf16x8*)(aBase0 + buf + kb);
      bf16x8 a1 = *(const bf16x8*)(aBase1 + buf + kb);
      acc0 = __builtin_amdgcn_mfma_f32_16x16x32_bf16(a0, b, acc0, 0, 0, 0);
      acc1 = __builtin_amdgcn_mfma_f32_16x16x32_bf16(a1, b, acc1, 0, 0, 0);
    }
    __builtin_amdgcn_sched_barrier(0);
    asm volatile("s_waitcnt vmcnt(0)" ::: "memory");
    __builtin_amdgcn_s_barrier();
    __builtin_amdgcn_sched_barrier(0);
  }
#undef STAGE

  // gate buffer aliases buf0 (safe: last reads of buf0 were iter 14, fenced)
  float* gl = (float*)smem;                 // [4][64][16]
  #pragma unroll
  for (int i = 0; i < 2; ++i) {
    f32x4 a = i ? acc1 : acc0;
    #pragma unroll
    for (int r = 0; r < 4; ++r) {
      int batch = mt * 32 + i * 16 + lg * 4 + r;
      gl[(g * 64 + batch) * 16 + lr] = a[r];
    }
  }
  __syncthreads();

  #pragma unroll
  for (int q = 0; q < 2; ++q) {
    int idx = q * 512 + tid;
    int batch = idx >> 4, col = idx & 15;
    int nb = cb * 16 + col;
    const unsigned short* xrow = xg + ((long)t * 64 + batch) * 8192;
    float iv = gl[(0 * 64 + batch) * 16 + col] + bf2f(xrow[nb]);
    float fv = gl[(1 * 64 + batch) * 16 + col] + bf2f(xrow[2048 + nb]);
    float gv = gl[(2 * 64 + batch) * 16 + col] + bf2f(xrow[4096 + nb]);
    float ov = gl[(3 * 64 + batch) * 16 + col] + bf2f(xrow[6144 + nb]);
    long ci = (long)batch * 2048 + nb;
    float c = sigm(fv) * Cstate[ci] + sigm(iv) * tanh_(gv);
    float h = sigm(ov) * tanh_(c);
    Cstate[ci] = c;
    Call_t[ci] = f2bf(c);
    Hnext[ci] = f2bf(h);
  }
}

// ---------------------------------------------------------------- heads (unchanged)
__global__ __launch_bounds__(256) void heads(
    const unsigned short* __restrict__ Hall,
    const unsigned short* __restrict__ Call,
    const float* __restrict__ Wp, const float* __restrict__ bp,
    const float* __restrict__ Wpc, const float* __restrict__ bpc,
    const float* __restrict__ Wu, const float* __restrict__ bu,
    const float* __restrict__ Wuse, const float* __restrict__ buse,
    const float* __restrict__ gum,
    float* __restrict__ out) {
  int p = blockIdx.x * 4 + (threadIdx.x >> 6);
  int l = threadIdx.x & 63;
  int t = p >> 6, b = p & 63;
  const unsigned short* h = Hall + ((long)(t + 1) * 64 + b) * 2048;
  const unsigned short* c = Call + ((long)t * 64 + b) * 2048;
  float s0 = 0, s1 = 0, sc0 = 0, sc1 = 0, su = 0, q0 = 0, q1 = 0;
  #pragma unroll
  for (int j = 0; j < 8; ++j) {
    int k = j * 256 + l * 4;
    ushort4 hv = *(const ushort4*)(h + k);
    ushort4 cv = *(const ushort4*)(c + k);
    float hf0 = bf2f(hv.x), hf1 = bf2f(hv.y), hf2 = bf2f(hv.z), hf3 = bf2f(hv.w);
    float cf0 = bf2f(cv.x), cf1 = bf2f(cv.y), cf2 = bf2f(cv.z), cf3 = bf2f(cv.w);
    float4 w0 = *(const float4*)(Wp + k);
    float4 w1 = *(const float4*)(Wp + 2048 + k);
    float4 w2 = *(const float4*)(Wpc + k);
    float4 w3 = *(const float4*)(Wpc + 2048 + k);
    float4 w4 = *(const float4*)(Wu + k);
    float4 w5 = *(const float4*)(Wuse + k);
    float4 w6 = *(const float4*)(Wuse + 2048 + k);
    s0 += hf0 * w0.x + hf1 * w0.y + hf2 * w0.z + hf3 * w0.w;
    s1 += hf0 * w1.x + hf1 * w1.y + hf2 * w1.z + hf3 * w1.w;
    sc0 += cf0 * w2.x + cf1 * w2.y + cf2 * w2.z + cf3 * w2.w;
    sc1 += cf0 * w3.x + cf1 * w3.y + cf2 * w3.z + cf3 * w3.w;
    su += hf0 * w4.x + hf1 * w4.y + hf2 * w4.z + hf3 * w4.w;
    q0 += hf0 * w5.x + hf1 * w5.y + hf2 * w5.z + hf3 * w5.w;
    q1 += hf0 * w6.x + hf1 * w6.y + hf2 * w6.z + hf3 * w6.w;
  }
  #pragma unroll
  for (int off = 32; off > 0; off >>= 1) {
    s0 += __shfl_xor(s0, off);
    s1 += __shfl_xor(s1, off);
    sc0 += __shfl_xor(sc0, off);
    sc1 += __shfl_xor(sc1, off);
    su += __shfl_xor(su, off);
    q0 += __shfl_xor(q0, off);
    q1 += __shfl_xor(q1, off);
  }
  if (l == 0) {
    out[(p << 1)] = s0 + bp[0];
    out[(p << 1) + 1] = s1 + bp[1];
    out[12288 + (p << 1)] = sc0 + bpc[0];
    out[12288 + (p << 1) + 1] = sc1 + bpc[1];
    out[24576 + p] = su + bu[0];
    float u0 = q0 + buse[0] + gum[p * 2];
    float u1 = q1 + buse[1] + gum[p * 2 + 1];
    float m = fmaxf(u0, u1);
    float x0 = expf(u0 - m), x1 = expf(u1 - m);
    float inv = 1.f / (x0 + x1);
    if (t >= 1) {
      out[30720 + ((t - 1) * 64 + b) * 2] = x0 * inv;
      out[30720 + ((t - 1) * 64 + b) * 2 + 1] = x1 * inv;
    }
  }
}

// ---------------------------------------------------------------- launch
extern "C" void kernel_launch(void* const* d_in, const int* in_sizes, int n_in,
                              void* d_out, int out_size, void* d_ws, size_t ws_size,
                              hipStream_t stream) {
  const float* feature  = (const float*)d_in[0];
  const float* W_ih     = (const float*)d_in[1];
  const float* W_hh     = (const float*)d_in[2];
  const float* b_ih     = (const float*)d_in[3];
  const float* b_hh     = (const float*)d_in[4];
  const float* W_pred   = (const float*)d_in[5];
  const float* b_pred   = (const float*)d_in[6];
  const float* W_pred_c = (const float*)d_in[7];
  const float* b_pred_c = (const float*)d_in[8];
  const float* W_util   = (const float*)d_in[9];
  const float* b_util   = (const float*)d_in[10];
  const float* W_use    = (const float*)d_in[11];
  const float* b_use    = (const float*)d_in[12];

  char* ws = (char*)d_ws;
  unsigned short* Abf  = (unsigned short*)(ws + 0);
  unsigned short* Call = (unsigned short*)(ws + 0);       // aliases Abf after phase 1
  unsigned short* Wbf  = (unsigned short*)(ws + 25165824L);
  unsigned short* xg   = (unsigned short*)(ws + 58720256L);
  unsigned short* Hall = (unsigned short*)(ws + 159383552L);
  float* Cstate        = (float*)(ws + 184811520L);
  float* gum           = (float*)(ws + 185335808L);
  float* out = (float*)d_out;

  hipMemsetAsync(Hall, 0, (size_t)BATCH * HID * 2, stream);
  hipMemsetAsync(Cstate, 0, (size_t)BATCH * HID * 4, stream);

  gumbel_k<<<48, 256, 0, stream>>>(gum);

  cast_bf16<<<(12582912 / 4) / 256, 256, 0, stream>>>(feature, Abf, 12582912 / 4);
  cast_bf16<<<(16777216 / 4) / 256, 256, 0, stream>>>(W_ih, Wbf, 16777216 / 4);

  gemm_xg<<<3072, 256, 0, stream>>>(Abf, Wbf, b_ih, b_hh, xg);

  cast_bf16<<<(16777216 / 4) / 256, 256, 0, stream>>>(W_hh, Wbf, 16777216 / 4);

  for (int t = 0; t < T_STEPS; ++t) {
    lstm_step<<<128, 512, 0, stream>>>(
        Wbf, xg,
        Hall + (long)t * BATCH * HID,
        Hall + (long)(t + 1) * BATCH * HID,
        Call + (long)t * BATCH * HID,
        Cstate, t);
  }

  heads<<<1536, 256, 0, stream>>>(Hall, Call,
                                  W_pred, b_pred, W_pred_c, b_pred_c,
                                  W_util, b_util, W_use, b_use,
                                  gum, out);
}

// Round 4
// 1320.799 us; speedup vs baseline: 2.5058x; 1.2351x over previous
//
#include <hip/hip_runtime.h>

typedef __attribute__((ext_vector_type(8))) short bf16x8;
typedef __attribute__((ext_vector_type(4))) float f32x4;

#define T_STEPS 96
#define BATCH 64
#define HID 2048
#define NGATE 8192

#define AS1 __attribute__((address_space(1)))
#define AS3 __attribute__((address_space(3)))

__device__ inline unsigned short f2bf(float f) {
  union { float f; unsigned u; } x; x.f = f;
  unsigned r = x.u + 0x7fffu + ((x.u >> 16) & 1u);
  return (unsigned short)(r >> 16);
}
__device__ inline float bf2f(unsigned short b) {
  union { unsigned u; float f; } x; x.u = ((unsigned)b) << 16;
  return x.f;
}
__device__ inline float sigm(float x) { return 1.f / (1.f + __expf(-x)); }
__device__ inline float tanh_(float x) { return 1.f - 2.f / (__expf(2.f * x) + 1.f); }

// ---------------------------------------------------------------- cast f32->bf16
__global__ __launch_bounds__(256) void cast_bf16(const float* __restrict__ in,
                                                 unsigned short* __restrict__ out,
                                                 int n4) {
  int i = blockIdx.x * 256 + threadIdx.x;
  if (i >= n4) return;
  float4 v = ((const float4*)in)[i];
  ushort4 o;
  o.x = f2bf(v.x); o.y = f2bf(v.y); o.z = f2bf(v.z); o.w = f2bf(v.w);
  ((ushort4*)out)[i] = o;
}

// ---------------------------------------------------------------- gumbel (threefry, partitionable)
__global__ void gumbel_k(float* __restrict__ g) {
  int p = blockIdx.x * blockDim.x + threadIdx.x;
  if (p >= 12288) return;
  const unsigned k1 = 0u, k2 = 42u;
  unsigned ks[3] = { k1, k2, 0x1BD11BDAu ^ k1 ^ k2 };
  unsigned x0 = 0u + ks[0];
  unsigned x1 = (unsigned)p + ks[1];
  const int rot[2][4] = { {13, 15, 26, 6}, {17, 29, 16, 24} };
  #pragma unroll
  for (int i = 0; i < 5; ++i) {
    #pragma unroll
    for (int j = 0; j < 4; ++j) {
      int r = rot[i & 1][j];
      x0 += x1;
      x1 = (x1 << r) | (x1 >> (32 - r));
      x1 ^= x0;
    }
    x0 += ks[(i + 1) % 3];
    x1 += ks[(i + 2) % 3] + (unsigned)(i + 1);
  }
  unsigned bits = x0 ^ x1;
  union { unsigned u; float f; } v; v.u = (bits >> 9) | 0x3f800000u;
  float f = v.f - 1.f;
  const float tiny = 1.17549435e-38f;
  float u = fmaxf(tiny, f * (1.f - tiny) + tiny);
  g[p] = -logf(-logf(u));
}

// ---------------------------------------------------------------- phase-1 GEMM (unchanged)
__global__ __launch_bounds__(256) void gemm_xg(
    const unsigned short* __restrict__ A,
    const unsigned short* __restrict__ W,
    const float* __restrict__ b_ih, const float* __restrict__ b_hh,
    unsigned short* __restrict__ xg) {
  __shared__ unsigned short As[128 * 32];
  __shared__ unsigned short Bs[128 * 32];
  int bid = blockIdx.x;
  int nb = bid & 63, mb = bid >> 6;
  int m0 = mb * 128, n0 = nb * 128;
  int tid = threadIdx.x, w = tid >> 6, l = tid & 63;
  int lr = l & 15, lg = l >> 4;
  int wm = (w & 1) * 64, wn = (w >> 1) * 64;
  f32x4 acc[4][4] = {};
  int e0 = w * 512 + l * 8;
  for (int k0 = 0; k0 < 2048; k0 += 32) {
    __syncthreads();
    #pragma unroll
    for (int j = 0; j < 2; ++j) {
      int e = j * 2048 + e0;
      int r = e >> 5, c = e & 31;
      const unsigned short* ga = A + (long)(m0 + r) * 2048 + k0 + c;
      const unsigned short* gb = W + (long)(n0 + r) * 2048 + k0 + c;
      __builtin_amdgcn_global_load_lds(
          (const AS1 unsigned int*)ga,
          (AS3 unsigned int*)&As[j * 2048 + w * 512], 16, 0, 0);
      __builtin_amdgcn_global_load_lds(
          (const AS1 unsigned int*)gb,
          (AS3 unsigned int*)&Bs[j * 2048 + w * 512], 16, 0, 0);
    }
    __syncthreads();
    bf16x8 av[4], bv[4];
    #pragma unroll
    for (int i = 0; i < 4; ++i)
      av[i] = *(const bf16x8*)&As[(wm + i * 16 + lr) * 32 + lg * 8];
    #pragma unroll
    for (int i = 0; i < 4; ++i)
      bv[i] = *(const bf16x8*)&Bs[(wn + i * 16 + lr) * 32 + lg * 8];
    #pragma unroll
    for (int i = 0; i < 4; ++i)
      #pragma unroll
      for (int j = 0; j < 4; ++j)
        acc[i][j] = __builtin_amdgcn_mfma_f32_16x16x32_bf16(av[i], bv[j], acc[i][j], 0, 0, 0);
  }
  #pragma unroll
  for (int j = 0; j < 4; ++j) {
    int n = n0 + wn + j * 16 + lr;
    float bias = b_ih[n] + b_hh[n];
    #pragma unroll
    for (int i = 0; i < 4; ++i) {
      #pragma unroll
      for (int r = 0; r < 4; ++r) {
        int m = m0 + wm + i * 16 + lg * 4 + r;
        int bb = m / 96;
        int tt = m - bb * 96;
        long row = (long)tt * 64 + bb;
        xg[row * 8192 + n] = f2bf(acc[i][j][r] + bias);
      }
    }
  }
}

// ---------------------------------------------------------------- recurrent step
// grid 256 (each block: 8 h-cols x 4 gates = 32 W-rows), block 512 = 8 waves.
// Wave w: Mtile (w&3) of 16 batches x Ntile (w>>2) of 16 W-rows.
// 3-buffer LDS ring, K-step 128, counted vmcnt(3) (one stage = 3 gload_lds/thread
// stays in flight across the barrier), XOR-swizzle (kbyte ^ (row&7)<<4) via
// pre-swizzled global source + swizzled ds_read. Fused gate combine + c/h.
__global__ __launch_bounds__(512) void lstm_step(
    const unsigned short* __restrict__ Whh,   // (8192,2048) bf16
    const unsigned short* __restrict__ xg,    // (96,64,8192) bf16
    const unsigned short* __restrict__ Hprev, // (64,2048) bf16
    unsigned short* __restrict__ Hnext,       // (64,2048) bf16
    unsigned short* __restrict__ Call_t,      // (64,2048) bf16 snapshot
    float* __restrict__ Cstate,               // (64,2048) f32
    int t) {
  __shared__ unsigned char smem[3 * 24576 + 8192];  // ring (A 16K + B 8K per buf) + gl 8K
  const int cb = blockIdx.x;
  const int tid = threadIdx.x;
  const int w = tid >> 6, l = tid & 63;
  const int lr = l & 15, lg = l >> 4;
  const int mtile = w & 3, ntile = w >> 2;

  // staging source addresses (linear LDS dest; logical kbyte = lin ^ ((row&7)<<4))
  const int lane16 = l & 15, lrow = l >> 4;
  const int rowA0 = w * 4 + lrow;            // A round 0: rows 0..31
  const int rowA1 = 32 + rowA0;              // A round 1: rows 32..63
  const int rowB  = w * 4 + lrow;            // B: rows 0..31
  const int kszA0 = (lane16 * 16) ^ ((rowA0 & 7) << 4);
  const int kszA1 = (lane16 * 16) ^ ((rowA1 & 7) << 4);
  const int kszB  = (lane16 * 16) ^ ((rowB & 7) << 4);
  const int WrowB = (rowB >> 3) * 2048 + cb * 8 + (rowB & 7);
  const unsigned short* aS0 = Hprev + (long)rowA0 * 2048 + (kszA0 >> 1);
  const unsigned short* aS1 = Hprev + (long)rowA1 * 2048 + (kszA1 >> 1);
  const unsigned short* bS  = Whh + (long)WrowB * 2048 + (kszB >> 1);

#define STAGE(bufi, k0) do {                                                    \
    unsigned char* lb = smem + (bufi) * 24576 + w * 1024;                       \
    __builtin_amdgcn_global_load_lds((const AS1 unsigned int*)(aS0 + (k0)),     \
        (AS3 unsigned int*)(lb), 16, 0, 0);                                     \
    __builtin_amdgcn_global_load_lds((const AS1 unsigned int*)(aS1 + (k0)),     \
        (AS3 unsigned int*)(lb + 8192), 16, 0, 0);                              \
    __builtin_amdgcn_global_load_lds((const AS1 unsigned int*)(bS + (k0)),      \
        (AS3 unsigned int*)(lb + 16384), 16, 0, 0);                             \
  } while (0)

  STAGE(0, 0);
  STAGE(1, 128);

  f32x4 acc = {};
  const int kx = (lr & 7) << 4;
  const int aOff = (mtile * 16 + lr) * 256;
  const int bOff = 16384 + (ntile * 16 + lr) * 256;

  for (int ks = 0; ks < 16; ++ks) {
    if (ks < 15) asm volatile("s_waitcnt vmcnt(3)" ::: "memory");
    else         asm volatile("s_waitcnt vmcnt(0)" ::: "memory");
    __builtin_amdgcn_s_barrier();
    __builtin_amdgcn_sched_barrier(0);
    if (ks < 14) STAGE((ks + 2) % 3, (ks + 2) * 128);
    const unsigned char* bufp = smem + (ks % 3) * 24576;
    __builtin_amdgcn_s_setprio(1);
    #pragma unroll
    for (int ksub = 0; ksub < 4; ++ksub) {
      int kb = (ksub * 64 + lg * 16) ^ kx;
      bf16x8 a = *(const bf16x8*)(bufp + aOff + kb);
      bf16x8 b = *(const bf16x8*)(bufp + bOff + kb);
      acc = __builtin_amdgcn_mfma_f32_16x16x32_bf16(a, b, acc, 0, 0, 0);
    }
    __builtin_amdgcn_s_setprio(0);
    __builtin_amdgcn_sched_barrier(0);
  }
#undef STAGE

  // gate exchange via separate LDS region (no ring aliasing)
  float* gl = (float*)(smem + 73728);        // [gate:4][batch:64][col:8]
  __syncthreads();
  {
    const int gate = ntile * 2 + (lr >> 3);
    const int col = lr & 7;
    #pragma unroll
    for (int r = 0; r < 4; ++r) {
      int batch = mtile * 16 + lg * 4 + r;
      gl[gate * 512 + batch * 8 + col] = acc[r];
    }
  }
  __syncthreads();

  // elementwise: one cell per thread (64 batches x 8 cols)
  {
    const int batch = tid >> 3, col = tid & 7;
    const int nb = cb * 8 + col;
    const unsigned short* xrow = xg + ((long)t * 64 + batch) * 8192;
    float iv = gl[tid]        + bf2f(xrow[nb]);
    float fv = gl[512 + tid]  + bf2f(xrow[2048 + nb]);
    float gv = gl[1024 + tid] + bf2f(xrow[4096 + nb]);
    float ov = gl[1536 + tid] + bf2f(xrow[6144 + nb]);
    long ci = (long)batch * 2048 + nb;
    float c = sigm(fv) * Cstate[ci] + sigm(iv) * tanh_(gv);
    float h = sigm(ov) * tanh_(c);
    Cstate[ci] = c;
    Call_t[ci] = f2bf(c);
    Hnext[ci] = f2bf(h);
  }
}

// ---------------------------------------------------------------- heads (unchanged)
__global__ __launch_bounds__(256) void heads(
    const unsigned short* __restrict__ Hall,
    const unsigned short* __restrict__ Call,
    const float* __restrict__ Wp, const float* __restrict__ bp,
    const float* __restrict__ Wpc, const float* __restrict__ bpc,
    const float* __restrict__ Wu, const float* __restrict__ bu,
    const float* __restrict__ Wuse, const float* __restrict__ buse,
    const float* __restrict__ gum,
    float* __restrict__ out) {
  int p = blockIdx.x * 4 + (threadIdx.x >> 6);
  int l = threadIdx.x & 63;
  int t = p >> 6, b = p & 63;
  const unsigned short* h = Hall + ((long)(t + 1) * 64 + b) * 2048;
  const unsigned short* c = Call + ((long)t * 64 + b) * 2048;
  float s0 = 0, s1 = 0, sc0 = 0, sc1 = 0, su = 0, q0 = 0, q1 = 0;
  #pragma unroll
  for (int j = 0; j < 8; ++j) {
    int k = j * 256 + l * 4;
    ushort4 hv = *(const ushort4*)(h + k);
    ushort4 cv = *(const ushort4*)(c + k);
    float hf0 = bf2f(hv.x), hf1 = bf2f(hv.y), hf2 = bf2f(hv.z), hf3 = bf2f(hv.w);
    float cf0 = bf2f(cv.x), cf1 = bf2f(cv.y), cf2 = bf2f(cv.z), cf3 = bf2f(cv.w);
    float4 w0 = *(const float4*)(Wp + k);
    float4 w1 = *(const float4*)(Wp + 2048 + k);
    float4 w2 = *(const float4*)(Wpc + k);
    float4 w3 = *(const float4*)(Wpc + 2048 + k);
    float4 w4 = *(const float4*)(Wu + k);
    float4 w5 = *(const float4*)(Wuse + k);
    float4 w6 = *(const float4*)(Wuse + 2048 + k);
    s0 += hf0 * w0.x + hf1 * w0.y + hf2 * w0.z + hf3 * w0.w;
    s1 += hf0 * w1.x + hf1 * w1.y + hf2 * w1.z + hf3 * w1.w;
    sc0 += cf0 * w2.x + cf1 * w2.y + cf2 * w2.z + cf3 * w2.w;
    sc1 += cf0 * w3.x + cf1 * w3.y + cf2 * w3.z + cf3 * w3.w;
    su += hf0 * w4.x + hf1 * w4.y + hf2 * w4.z + hf3 * w4.w;
    q0 += hf0 * w5.x + hf1 * w5.y + hf2 * w5.z + hf3 * w5.w;
    q1 += hf0 * w6.x + hf1 * w6.y + hf2 * w6.z + hf3 * w6.w;
  }
  #pragma unroll
  for (int off = 32; off > 0; off >>= 1) {
    s0 += __shfl_xor(s0, off);
    s1 += __shfl_xor(s1, off);
    sc0 += __shfl_xor(sc0, off);
    sc1 += __shfl_xor(sc1, off);
    su += __shfl_xor(su, off);
    q0 += __shfl_xor(q0, off);
    q1 += __shfl_xor(q1, off);
  }
  if (l == 0) {
    out[(p << 1)] = s0 + bp[0];
    out[(p << 1) + 1] = s1 + bp[1];
    out[12288 + (p << 1)] = sc0 + bpc[0];
    out[12288 + (p << 1) + 1] = sc1 + bpc[1];
    out[24576 + p] = su + bu[0];
    float u0 = q0 + buse[0] + gum[p * 2];
    float u1 = q1 + buse[1] + gum[p * 2 + 1];
    float m = fmaxf(u0, u1);
    float x0 = expf(u0 - m), x1 = expf(u1 - m);
    float inv = 1.f / (x0 + x1);
    if (t >= 1) {
      out[30720 + ((t - 1) * 64 + b) * 2] = x0 * inv;
      out[30720 + ((t - 1) * 64 + b) * 2 + 1] = x1 * inv;
    }
  }
}

// ---------------------------------------------------------------- launch
extern "C" void kernel_launch(void* const* d_in, const int* in_sizes, int n_in,
                              void* d_out, int out_size, void* d_ws, size_t ws_size,
                              hipStream_t stream) {
  const float* feature  = (const float*)d_in[0];
  const float* W_ih     = (const float*)d_in[1];
  const float* W_hh     = (const float*)d_in[2];
  const float* b_ih     = (const float*)d_in[3];
  const float* b_hh     = (const float*)d_in[4];
  const float* W_pred   = (const float*)d_in[5];
  const float* b_pred   = (const float*)d_in[6];
  const float* W_pred_c = (const float*)d_in[7];
  const float* b_pred_c = (const float*)d_in[8];
  const float* W_util   = (const float*)d_in[9];
  const float* b_util   = (const float*)d_in[10];
  const float* W_use    = (const float*)d_in[11];
  const float* b_use    = (const float*)d_in[12];

  char* ws = (char*)d_ws;
  unsigned short* Abf  = (unsigned short*)(ws + 0);
  unsigned short* Call = (unsigned short*)(ws + 0);       // aliases Abf after phase 1
  unsigned short* Wbf  = (unsigned short*)(ws + 25165824L);
  unsigned short* xg   = (unsigned short*)(ws + 58720256L);
  unsigned short* Hall = (unsigned short*)(ws + 159383552L);
  float* Cstate        = (float*)(ws + 184811520L);
  float* gum           = (float*)(ws + 185335808L);
  float* out = (float*)d_out;

  hipMemsetAsync(Hall, 0, (size_t)BATCH * HID * 2, stream);
  hipMemsetAsync(Cstate, 0, (size_t)BATCH * HID * 4, stream);

  gumbel_k<<<48, 256, 0, stream>>>(gum);

  cast_bf16<<<(12582912 / 4) / 256, 256, 0, stream>>>(feature, Abf, 12582912 / 4);
  cast_bf16<<<(16777216 / 4) / 256, 256, 0, stream>>>(W_ih, Wbf, 16777216 / 4);

  gemm_xg<<<3072, 256, 0, stream>>>(Abf, Wbf, b_ih, b_hh, xg);

  cast_bf16<<<(16777216 / 4) / 256, 256, 0, stream>>>(W_hh, Wbf, 16777216 / 4);

  for (int t = 0; t < T_STEPS; ++t) {
    lstm_step<<<256, 512, 0, stream>>>(
        Wbf, xg,
        Hall + (long)t * BATCH * HID,
        Hall + (long)(t + 1) * BATCH * HID,
        Call + (long)t * BATCH * HID,
        Cstate, t);
  }

  heads<<<1536, 256, 0, stream>>>(Hall, Call,
                                  W_pred, b_pred, W_pred_c, b_pred_c,
                                  W_util, b_util, W_use, b_use,
                                  gum, out);
}